// Round 1
// baseline (1347.365 us; speedup 1.0000x reference)
//
#include <hip/hip_runtime.h>
#include <hip/hip_bf16.h>

#define N_NODES 50000
#define N_EDGES 800000
#define N_GRAPHS 256
#define HID 64
#define KOUT 192   // K * OUT
#define EPS 1e-5f

// ---------------- degree ----------------
__global__ void k_deg(const int* __restrict__ dst, int* __restrict__ deg) {
    int i = blockIdx.x * blockDim.x + threadIdx.x;
    if (i < N_EDGES) atomicAdd(&deg[dst[i]], 1);
}

__global__ void k_dinv(const int* __restrict__ deg, float* __restrict__ dinv) {
    int i = blockIdx.x * blockDim.x + threadIdx.x;
    if (i < N_NODES) dinv[i] = rsqrtf((float)deg[i] + 1.0f);
}

// ---------------- h = emb[h_idx] ----------------
__global__ void k_hinit(const int* __restrict__ h_idx, const float* __restrict__ emb,
                        float* __restrict__ h) {
    int i = blockIdx.x * blockDim.x + threadIdx.x;
    if (i < N_NODES * HID) {
        int n = i >> 6, c = i & 63;
        h[i] = emb[h_idx[n] * HID + c];
    }
}

// ---------------- hk = h @ fc_w[l].T  (N x 192) ----------------
// block: 192 threads, each holds its weight row (64 f32) in registers,
// processes 64 nodes (h row broadcast from LDS).
__global__ __launch_bounds__(192) void k_fc(const float* __restrict__ h,
                                            const float* __restrict__ fcw,
                                            float* __restrict__ hk) {
    __shared__ float sh[HID];
    int j = threadIdx.x;
    float w[HID];
    const float4* wrow = (const float4*)(fcw + j * HID);
#pragma unroll
    for (int i = 0; i < HID / 4; ++i) ((float4*)w)[i] = wrow[i];
    int n0 = blockIdx.x * 64;
    int n1 = min(n0 + 64, N_NODES);
    for (int n = n0; n < n1; ++n) {
        __syncthreads();
        if (j < HID) sh[j] = h[(size_t)n * HID + j];
        __syncthreads();
        float acc = 0.f;
#pragma unroll
        for (int i = 0; i < HID; ++i) acc = fmaf(sh[i], w[i], acc);
        hk[(size_t)n * KOUT + j] = acc;
    }
}

// ---------------- per-edge gaussian weights ----------------
__global__ void k_gauss(const int* __restrict__ src, const int* __restrict__ dst,
                        const float* __restrict__ dinv, float4* __restrict__ gauss,
                        const float* __restrict__ mu, const float* __restrict__ isg,
                        const float* __restrict__ ppw, const float* __restrict__ ppb) {
    int e = blockIdx.x * blockDim.x + threadIdx.x;
    if (e >= N_EDGES) return;
    float p0 = dinv[src[e]];
    float p1 = dinv[dst[e]];
    float u0 = tanhf(fmaf(p1, ppw[1], fmaf(p0, ppw[0], ppb[0])));
    float u1 = tanhf(fmaf(p1, ppw[3], fmaf(p0, ppw[2], ppb[1])));
    float4 g;
    float t0, t1;
    t0 = (u0 - mu[0]) * isg[0]; t1 = (u1 - mu[1]) * isg[1];
    g.x = __expf(-0.5f * (t0 * t0 + t1 * t1));
    t0 = (u0 - mu[2]) * isg[2]; t1 = (u1 - mu[3]) * isg[3];
    g.y = __expf(-0.5f * (t0 * t0 + t1 * t1));
    t0 = (u0 - mu[4]) * isg[4]; t1 = (u1 - mu[5]) * isg[5];
    g.z = __expf(-0.5f * (t0 * t0 + t1 * t1));
    g.w = 0.f;
    gauss[e] = g;
}

// ---------------- edge aggregation: one wave per edge ----------------
__global__ void k_edge_agg(const int* __restrict__ src, const int* __restrict__ dst,
                           const float4* __restrict__ gauss, const float* __restrict__ hk,
                           float* __restrict__ agg) {
    int idx = blockIdx.x * blockDim.x + threadIdx.x;
    int e = idx >> 6;
    int lane = idx & 63;
    if (e >= N_EDGES) return;
    int s = src[e], d = dst[e];
    float4 g = gauss[e];
    const float* hks = hk + (size_t)s * KOUT + lane;
    float val = g.x * hks[0] + g.y * hks[64] + g.z * hks[128];
    atomicAdd(&agg[(size_t)d * HID + lane], val);
}

// ---------------- BN: partial sums (sum, sumsq per channel) ----------------
__global__ void k_bnred(const float* __restrict__ agg, float* __restrict__ bnsum) {
    __shared__ float sred[512];
    int c = threadIdx.x & 63;
    int r = threadIdx.x >> 6;
    int base = blockIdx.x * 256;
    int end = min(base + 256, N_NODES);
    float s = 0.f, q = 0.f;
    for (int n = base + r; n < end; n += 4) {
        float v = agg[(size_t)n * HID + c];
        s += v; q += v * v;
    }
    sred[threadIdx.x] = s;
    sred[256 + threadIdx.x] = q;
    __syncthreads();
    if (threadIdx.x < 64) {
        s = sred[c] + sred[64 + c] + sred[128 + c] + sred[192 + c];
        q = sred[256 + c] + sred[320 + c] + sred[384 + c] + sred[448 + c];
        atomicAdd(&bnsum[c], s);
        atomicAdd(&bnsum[64 + c], q);
    }
}

__global__ void k_bnfin(const float* __restrict__ bnsum, const float* __restrict__ bng,
                        const float* __restrict__ bnb, float* __restrict__ bnsc) {
    int c = threadIdx.x;  // 64 threads
    const float invN = 1.0f / (float)N_NODES;
    float mean = bnsum[c] * invN;
    float var = bnsum[64 + c] * invN - mean * mean;
    float scale = bng[c] * rsqrtf(var + EPS);
    bnsc[c] = scale;
    bnsc[64 + c] = bnb[c] - mean * scale;
}

// h += relu(agg*scale + shift)
__global__ void k_bnapply(const float* __restrict__ agg, const float* __restrict__ bnsc,
                          float* __restrict__ h) {
    int i = blockIdx.x * blockDim.x + threadIdx.x;
    if (i < N_NODES * HID) {
        int c = i & 63;
        float hn = fmaf(agg[i], bnsc[c], bnsc[64 + c]);
        h[i] += fmaxf(hn, 0.f);
    }
}

// ---------------- readout ----------------
__global__ void k_readout(const float* __restrict__ h, const int* __restrict__ gid,
                          float* __restrict__ hg, float* __restrict__ cnt) {
    int i = blockIdx.x * blockDim.x + threadIdx.x;
    if (i < N_NODES * HID) {
        int n = i >> 6, c = i & 63;
        int g = gid[n];
        atomicAdd(&hg[(size_t)g * HID + c], h[i]);
        if (c == 0) atomicAdd(&cnt[g], 1.0f);
    }
}

// ---------------- MLP readout: one thread per graph ----------------
__global__ __launch_bounds__(256) void k_mlp(const float* __restrict__ hg,
                                             const float* __restrict__ cnt,
                                             const float* __restrict__ w1, const float* __restrict__ b1,
                                             const float* __restrict__ w2, const float* __restrict__ b2,
                                             const float* __restrict__ w3, const float* __restrict__ b3,
                                             float* __restrict__ out) {
    int g = threadIdx.x;  // 256 threads, single block
    float inv = 1.0f / fmaxf(cnt[g], 1.0f);
    float x[HID];
#pragma unroll
    for (int i = 0; i < HID; ++i) x[i] = hg[(size_t)g * HID + i] * inv;
    float y1[32];
#pragma unroll
    for (int j = 0; j < 32; ++j) {
        float acc = b1[j];
#pragma unroll
        for (int i = 0; i < HID; ++i) acc = fmaf(x[i], w1[j * HID + i], acc);
        y1[j] = fmaxf(acc, 0.f);
    }
    float y2[16];
#pragma unroll
    for (int j = 0; j < 16; ++j) {
        float acc = b2[j];
#pragma unroll
        for (int i = 0; i < 32; ++i) acc = fmaf(y1[i], w2[j * 32 + i], acc);
        y2[j] = fmaxf(acc, 0.f);
    }
    float acc = b3[0];
#pragma unroll
    for (int i = 0; i < 16; ++i) acc = fmaf(y2[i], w3[i], acc);
    out[g] = acc;
}

extern "C" void kernel_launch(void* const* d_in, const int* in_sizes, int n_in,
                              void* d_out, int out_size, void* d_ws, size_t ws_size,
                              hipStream_t stream) {
    const int* h_idx = (const int*)d_in[0];
    const int* src = (const int*)d_in[1];
    const int* dst = (const int*)d_in[2];
    const int* gid = (const int*)d_in[3];
    const float* emb = (const float*)d_in[4];
    const float* fc_w = (const float*)d_in[5];
    const float* mu = (const float*)d_in[6];
    const float* isg = (const float*)d_in[7];
    const float* bng = (const float*)d_in[8];
    const float* bnb = (const float*)d_in[9];
    const float* ppw = (const float*)d_in[10];
    const float* ppb = (const float*)d_in[11];
    const float* w1 = (const float*)d_in[12];
    const float* b1 = (const float*)d_in[13];
    const float* w2 = (const float*)d_in[14];
    const float* b2 = (const float*)d_in[15];
    const float* w3 = (const float*)d_in[16];
    const float* b3 = (const float*)d_in[17];

    char* ws = (char*)d_ws;
    size_t o = 0;
    auto take = [&](size_t bytes) -> char* {
        char* p = ws + o;
        o += (bytes + 255) & ~(size_t)255;
        return p;
    };
    int* deg = (int*)take((size_t)N_NODES * 4);
    float* dinv = (float*)take((size_t)N_NODES * 4);
    float* h = (float*)take((size_t)N_NODES * HID * 4);
    float* hk = (float*)take((size_t)N_NODES * KOUT * 4);
    float* agg = (float*)take((size_t)N_NODES * HID * 4);
    float4* gauss = (float4*)take((size_t)N_EDGES * 16);
    float* bnsum = (float*)take(128 * 4);
    float* bnsc = (float*)take(128 * 4);
    float* hg = (float*)take((size_t)N_GRAPHS * HID * 4);
    float* cnt = (float*)take((size_t)N_GRAPHS * 4);

    hipMemsetAsync(deg, 0, (size_t)N_NODES * 4, stream);
    k_deg<<<(N_EDGES + 255) / 256, 256, 0, stream>>>(dst, deg);
    k_dinv<<<(N_NODES + 255) / 256, 256, 0, stream>>>(deg, dinv);
    k_hinit<<<(N_NODES * HID + 255) / 256, 256, 0, stream>>>(h_idx, emb, h);

    for (int l = 0; l < 4; ++l) {
        k_fc<<<(N_NODES + 63) / 64, 192, 0, stream>>>(h, fc_w + (size_t)l * KOUT * HID, hk);
        k_gauss<<<(N_EDGES + 255) / 256, 256, 0, stream>>>(src, dst, dinv, gauss,
                                                           mu + l * 6, isg + l * 6,
                                                           ppw + l * 4, ppb + l * 2);
        hipMemsetAsync(agg, 0, (size_t)N_NODES * HID * 4, stream);
        hipMemsetAsync(bnsum, 0, 128 * 4, stream);
        k_edge_agg<<<(N_EDGES * 64) / 256, 256, 0, stream>>>(src, dst, gauss, hk, agg);
        k_bnred<<<(N_NODES + 255) / 256, 256, 0, stream>>>(agg, bnsum);
        k_bnfin<<<1, 64, 0, stream>>>(bnsum, bng + l * 64, bnb + l * 64, bnsc);
        k_bnapply<<<(N_NODES * HID + 255) / 256, 256, 0, stream>>>(agg, bnsc, h);
    }

    hipMemsetAsync(hg, 0, (size_t)(N_GRAPHS * HID + N_GRAPHS) * 4, stream);
    k_readout<<<(N_NODES * HID + 255) / 256, 256, 0, stream>>>(h, gid, hg, cnt);
    k_mlp<<<1, 256, 0, stream>>>(hg, cnt, w1, b1, w2, b2, w3, b3, (float*)d_out);
}

// Round 2
// 804.056 us; speedup vs baseline: 1.6757x; 1.6757x over previous
//
#include <hip/hip_runtime.h>
#include <hip/hip_bf16.h>

#define N_NODES 50000
#define N_EDGES 800000
#define N_GRAPHS 256
#define HID 64
#define KOUT 192   // K * OUT
#define EPS 1e-5f

// ---------------- degree ----------------
__global__ void k_deg(const int* __restrict__ dst, int* __restrict__ deg) {
    int i = blockIdx.x * blockDim.x + threadIdx.x;
    if (i < N_EDGES) atomicAdd(&deg[dst[i]], 1);
}

__global__ void k_dinv(const int* __restrict__ deg, float* __restrict__ dinv) {
    int i = blockIdx.x * blockDim.x + threadIdx.x;
    if (i < N_NODES) dinv[i] = rsqrtf((float)deg[i] + 1.0f);
}

// ---------------- rowptr = exclusive scan of deg (single block) ----------------
#define SCAN_T 1024
#define SCAN_CHUNK 49  // 1024*49 = 50176 >= 50000
__global__ __launch_bounds__(SCAN_T) void k_scan(const int* __restrict__ deg,
                                                 int* __restrict__ rowptr) {
    __shared__ int sc[SCAN_T];
    int t = threadIdx.x;
    int base = t * SCAN_CHUNK;
    int s = 0;
#pragma unroll
    for (int j = 0; j < SCAN_CHUNK; ++j) {
        int idx = base + j;
        if (idx < N_NODES) s += deg[idx];
    }
    sc[t] = s;
    __syncthreads();
    for (int off = 1; off < SCAN_T; off <<= 1) {
        int v = (t >= off) ? sc[t - off] : 0;
        __syncthreads();
        sc[t] += v;
        __syncthreads();
    }
    int run = sc[t] - s;  // exclusive prefix of this thread's chunk
    for (int j = 0; j < SCAN_CHUNK; ++j) {
        int idx = base + j;
        if (idx < N_NODES) { rowptr[idx] = run; run += deg[idx]; }
    }
    if (t == SCAN_T - 1) rowptr[N_NODES] = sc[SCAN_T - 1];
}

// ---------------- scatter edges into CSR (by dst) ----------------
__global__ void k_scatter(const int* __restrict__ src, const int* __restrict__ dst,
                          const int* __restrict__ rowptr, int* __restrict__ cursor,
                          const float* __restrict__ dinv,
                          int* __restrict__ csr_src, float2* __restrict__ csr_pse) {
    int e = blockIdx.x * blockDim.x + threadIdx.x;
    if (e >= N_EDGES) return;
    int s = src[e], d = dst[e];
    int p = rowptr[d] + atomicAdd(&cursor[d], 1);
    csr_src[p] = s;
    csr_pse[p] = make_float2(dinv[s], dinv[d]);
}

// ---------------- h = emb[h_idx] ----------------
__global__ void k_hinit(const int* __restrict__ h_idx, const float* __restrict__ emb,
                        float* __restrict__ h) {
    int i = blockIdx.x * blockDim.x + threadIdx.x;
    if (i < N_NODES * HID) {
        int n = i >> 6, c = i & 63;
        h[i] = emb[h_idx[n] * HID + c];
    }
}

// ---------------- per-edge gaussian weights (CSR order) ----------------
__global__ void k_gauss(const float2* __restrict__ csr_pse, float4* __restrict__ gauss,
                        const float* __restrict__ mu, const float* __restrict__ isg,
                        const float* __restrict__ ppw, const float* __restrict__ ppb) {
    int e = blockIdx.x * blockDim.x + threadIdx.x;
    if (e >= N_EDGES) return;
    float2 ps = csr_pse[e];
    float u0 = tanhf(fmaf(ps.y, ppw[1], fmaf(ps.x, ppw[0], ppb[0])));
    float u1 = tanhf(fmaf(ps.y, ppw[3], fmaf(ps.x, ppw[2], ppb[1])));
    float4 g;
    float t0, t1;
    t0 = (u0 - mu[0]) * isg[0]; t1 = (u1 - mu[1]) * isg[1];
    g.x = __expf(-0.5f * (t0 * t0 + t1 * t1));
    t0 = (u0 - mu[2]) * isg[2]; t1 = (u1 - mu[3]) * isg[3];
    g.y = __expf(-0.5f * (t0 * t0 + t1 * t1));
    t0 = (u0 - mu[4]) * isg[4]; t1 = (u1 - mu[5]) * isg[5];
    g.z = __expf(-0.5f * (t0 * t0 + t1 * t1));
    g.w = 0.f;
    gauss[e] = g;
}

// ---------------- pull aggregation: one wave per node, no atomics ----------------
// a3[n, k, c] = sum over in-edges e of gauss[e][k] * h[src_e][c]
__global__ __launch_bounds__(256) void k_pull(const int* __restrict__ rowptr,
                                              const int* __restrict__ csr_src,
                                              const float4* __restrict__ gauss,
                                              const float* __restrict__ h,
                                              float* __restrict__ a3) {
    int n = blockIdx.x * 4 + (threadIdx.x >> 6);
    n = __builtin_amdgcn_readfirstlane(n);
    if (n >= N_NODES) return;
    int lane = threadIdx.x & 63;
    int beg = rowptr[n];
    int end = rowptr[n + 1];
    float a0 = 0.f, a1 = 0.f, a2 = 0.f;
    int p = beg;
    for (; p + 2 <= end; p += 2) {
        int s0 = csr_src[p];
        int s1 = csr_src[p + 1];
        float4 g0 = gauss[p];
        float4 g1 = gauss[p + 1];
        float h0 = h[(size_t)s0 * HID + lane];
        float h1 = h[(size_t)s1 * HID + lane];
        a0 = fmaf(g0.x, h0, a0); a1 = fmaf(g0.y, h0, a1); a2 = fmaf(g0.z, h0, a2);
        a0 = fmaf(g1.x, h1, a0); a1 = fmaf(g1.y, h1, a1); a2 = fmaf(g1.z, h1, a2);
    }
    if (p < end) {
        int s0 = csr_src[p];
        float4 g0 = gauss[p];
        float h0 = h[(size_t)s0 * HID + lane];
        a0 = fmaf(g0.x, h0, a0); a1 = fmaf(g0.y, h0, a1); a2 = fmaf(g0.z, h0, a2);
    }
    float* out = a3 + (size_t)n * KOUT + lane;
    out[0] = a0;
    out[64] = a1;
    out[128] = a2;
}

// ---------------- transform: agg[n,c'] = sum_{k,c} a3[n,k,c]*fcw[k*64+c',c] ----------------
// + fused BN partial sums. 256 threads: c' = t&63, quarter q = t>>6 covers j in [q*48,q*48+48)
__global__ __launch_bounds__(256) void k_fc2(const float* __restrict__ a3,
                                             const float* __restrict__ fcw,
                                             float* __restrict__ agg,
                                             float* __restrict__ bnsum) {
    int t = threadIdx.x;
    int cp = t & 63;
    int q = t >> 6;
    float w[48];
#pragma unroll
    for (int jj = 0; jj < 48; ++jj) {
        int j = q * 48 + jj;
        w[jj] = fcw[((j >> 6) * 64 + cp) * 64 + (j & 63)];
    }
    __shared__ float sa[KOUT];
    __shared__ float sp[4][64];
    float bnS = 0.f, bnQ = 0.f;
    for (int node = blockIdx.x; node < N_NODES; node += gridDim.x) {
        if (t < KOUT) sa[t] = a3[(size_t)node * KOUT + t];
        __syncthreads();
        float acc = 0.f;
#pragma unroll
        for (int jj = 0; jj < 48; ++jj) acc = fmaf(sa[q * 48 + jj], w[jj], acc);
        sp[q][cp] = acc;
        __syncthreads();
        if (q == 0) {
            float v = sp[0][cp] + sp[1][cp] + sp[2][cp] + sp[3][cp];
            agg[(size_t)node * HID + cp] = v;
            bnS += v;
            bnQ += v * v;
        }
    }
    if (q == 0) {
        atomicAdd(&bnsum[cp], bnS);
        atomicAdd(&bnsum[64 + cp], bnQ);
    }
}

__global__ void k_bnfin(const float* __restrict__ bnsum, const float* __restrict__ bng,
                        const float* __restrict__ bnb, float* __restrict__ bnsc) {
    int c = threadIdx.x;  // 64 threads
    const float invN = 1.0f / (float)N_NODES;
    float mean = bnsum[c] * invN;
    float var = bnsum[64 + c] * invN - mean * mean;
    float scale = bng[c] * rsqrtf(var + EPS);
    bnsc[c] = scale;
    bnsc[64 + c] = bnb[c] - mean * scale;
}

// h += relu(agg*scale + shift)
__global__ void k_bnapply(const float* __restrict__ agg, const float* __restrict__ bnsc,
                          float* __restrict__ h) {
    int i = blockIdx.x * blockDim.x + threadIdx.x;
    if (i < N_NODES * HID) {
        int c = i & 63;
        float hn = fmaf(agg[i], bnsc[c], bnsc[64 + c]);
        h[i] += fmaxf(hn, 0.f);
    }
}

// ---------------- readout: wave per 64-node chunk, run-length accumulate ----------------
__global__ __launch_bounds__(256) void k_readout(const float* __restrict__ h,
                                                 const int* __restrict__ gid,
                                                 float* __restrict__ hg,
                                                 float* __restrict__ cnt) {
    int chunk = blockIdx.x * 4 + (threadIdx.x >> 6);
    int lane = threadIdx.x & 63;
    int n0 = chunk * 64;
    if (n0 >= N_NODES) return;
    int n1 = min(n0 + 64, N_NODES);
    int curg = gid[n0];
    float acc = 0.f;
    int count = 0;
    for (int n = n0; n < n1; ++n) {
        int g = gid[n];
        if (g != curg) {
            atomicAdd(&hg[(size_t)curg * HID + lane], acc);
            if (lane == 0) atomicAdd(&cnt[curg], (float)count);
            curg = g; acc = 0.f; count = 0;
        }
        acc += h[(size_t)n * HID + lane];
        ++count;
    }
    atomicAdd(&hg[(size_t)curg * HID + lane], acc);
    if (lane == 0) atomicAdd(&cnt[curg], (float)count);
}

// ---------------- MLP readout ----------------
__global__ __launch_bounds__(256) void k_mlp(const float* __restrict__ hg,
                                             const float* __restrict__ cnt,
                                             const float* __restrict__ w1, const float* __restrict__ b1,
                                             const float* __restrict__ w2, const float* __restrict__ b2,
                                             const float* __restrict__ w3, const float* __restrict__ b3,
                                             float* __restrict__ out) {
    int g = threadIdx.x;  // 256 threads, single block
    float inv = 1.0f / fmaxf(cnt[g], 1.0f);
    float x[HID];
#pragma unroll
    for (int i = 0; i < HID; ++i) x[i] = hg[(size_t)g * HID + i] * inv;
    float y1[32];
#pragma unroll
    for (int j = 0; j < 32; ++j) {
        float acc = b1[j];
#pragma unroll
        for (int i = 0; i < HID; ++i) acc = fmaf(x[i], w1[j * HID + i], acc);
        y1[j] = fmaxf(acc, 0.f);
    }
    float y2[16];
#pragma unroll
    for (int j = 0; j < 16; ++j) {
        float acc = b2[j];
#pragma unroll
        for (int i = 0; i < 32; ++i) acc = fmaf(y1[i], w2[j * 32 + i], acc);
        y2[j] = fmaxf(acc, 0.f);
    }
    float acc = b3[0];
#pragma unroll
    for (int i = 0; i < 16; ++i) acc = fmaf(y2[i], w3[i], acc);
    out[g] = acc;
}

extern "C" void kernel_launch(void* const* d_in, const int* in_sizes, int n_in,
                              void* d_out, int out_size, void* d_ws, size_t ws_size,
                              hipStream_t stream) {
    const int* h_idx = (const int*)d_in[0];
    const int* src = (const int*)d_in[1];
    const int* dst = (const int*)d_in[2];
    const int* gid = (const int*)d_in[3];
    const float* emb = (const float*)d_in[4];
    const float* fc_w = (const float*)d_in[5];
    const float* mu = (const float*)d_in[6];
    const float* isg = (const float*)d_in[7];
    const float* bng = (const float*)d_in[8];
    const float* bnb = (const float*)d_in[9];
    const float* ppw = (const float*)d_in[10];
    const float* ppb = (const float*)d_in[11];
    const float* w1 = (const float*)d_in[12];
    const float* b1 = (const float*)d_in[13];
    const float* w2 = (const float*)d_in[14];
    const float* b2 = (const float*)d_in[15];
    const float* w3 = (const float*)d_in[16];
    const float* b3 = (const float*)d_in[17];

    char* ws = (char*)d_ws;
    size_t o = 0;
    auto take = [&](size_t bytes) -> char* {
        char* p = ws + o;
        o += (bytes + 255) & ~(size_t)255;
        return p;
    };
    int* deg = (int*)take((size_t)N_NODES * 4);
    float* dinv = (float*)take((size_t)N_NODES * 4);
    int* rowptr = (int*)take((size_t)(N_NODES + 1) * 4);
    int* cursor = (int*)take((size_t)N_NODES * 4);
    int* csr_src = (int*)take((size_t)N_EDGES * 4);
    float2* csr_pse = (float2*)take((size_t)N_EDGES * 8);
    float* h = (float*)take((size_t)N_NODES * HID * 4);
    float* a3 = (float*)take((size_t)N_NODES * KOUT * 4);
    // gauss (E*16B) and agg (N*64*4B) have disjoint lifetimes -> share one buffer
    char* shared_buf = take((size_t)N_EDGES * 16);
    float4* gauss = (float4*)shared_buf;
    float* agg = (float*)shared_buf;
    float* bnsum = (float*)take(128 * 4);
    float* bnsc = (float*)take(128 * 4);
    float* hg = (float*)take((size_t)N_GRAPHS * HID * 4);
    float* cnt = (float*)take((size_t)N_GRAPHS * 4);

    // ---- one-time graph preprocessing ----
    hipMemsetAsync(deg, 0, (size_t)N_NODES * 4, stream);
    hipMemsetAsync(cursor, 0, (size_t)N_NODES * 4, stream);
    k_deg<<<(N_EDGES + 255) / 256, 256, 0, stream>>>(dst, deg);
    k_dinv<<<(N_NODES + 255) / 256, 256, 0, stream>>>(deg, dinv);
    k_scan<<<1, SCAN_T, 0, stream>>>(deg, rowptr);
    k_scatter<<<(N_EDGES + 255) / 256, 256, 0, stream>>>(src, dst, rowptr, cursor,
                                                         dinv, csr_src, csr_pse);
    k_hinit<<<(N_NODES * HID + 255) / 256, 256, 0, stream>>>(h_idx, emb, h);

    for (int l = 0; l < 4; ++l) {
        k_gauss<<<(N_EDGES + 255) / 256, 256, 0, stream>>>(csr_pse, gauss,
                                                           mu + l * 6, isg + l * 6,
                                                           ppw + l * 4, ppb + l * 2);
        k_pull<<<(N_NODES + 3) / 4, 256, 0, stream>>>(rowptr, csr_src, gauss, h, a3);
        hipMemsetAsync(bnsum, 0, 128 * 4, stream);
        k_fc2<<<512, 256, 0, stream>>>(a3, fc_w + (size_t)l * KOUT * HID, agg, bnsum);
        k_bnfin<<<1, 64, 0, stream>>>(bnsum, bng + l * 64, bnb + l * 64, bnsc);
        k_bnapply<<<(N_NODES * HID + 255) / 256, 256, 0, stream>>>(agg, bnsc, h);
    }

    hipMemsetAsync(hg, 0, (size_t)(N_GRAPHS * HID + N_GRAPHS) * 4, stream);
    k_readout<<<(N_NODES / 64 + 3) / 4 + 1, 256, 0, stream>>>(h, gid, hg, cnt);
    k_mlp<<<1, 256, 0, stream>>>(hg, cnt, w1, b1, w2, b2, w3, b3, (float*)d_out);
}

// Round 3
// 669.452 us; speedup vs baseline: 2.0126x; 1.2011x over previous
//
#include <hip/hip_runtime.h>
#include <hip/hip_bf16.h>

#define N_NODES 50000
#define N_EDGES 800000
#define N_GRAPHS 256
#define HID 64
#define KOUT 192   // K * OUT
#define EPS 1e-5f
#define NB1 196    // ceil(N_NODES / 256)

// ---------------- degree ----------------
__global__ void k_deg(const int* __restrict__ dst, int* __restrict__ deg) {
    int i = blockIdx.x * blockDim.x + threadIdx.x;
    if (i < N_EDGES) atomicAdd(&deg[dst[i]], 1);
}

// ---------------- hierarchical exclusive scan of deg -> rowptr ----------------
__global__ __launch_bounds__(256) void k_scan1(const int* __restrict__ deg,
                                               int* __restrict__ rowptr,
                                               int* __restrict__ blocksum) {
    __shared__ int sc[256];
    int t = threadIdx.x;
    int i = blockIdx.x * 256 + t;
    int v = (i < N_NODES) ? deg[i] : 0;
    sc[t] = v;
    __syncthreads();
    for (int off = 1; off < 256; off <<= 1) {
        int u = (t >= off) ? sc[t - off] : 0;
        __syncthreads();
        sc[t] += u;
        __syncthreads();
    }
    if (i < N_NODES) rowptr[i] = sc[t] - v;  // exclusive local prefix
    if (t == 255) blocksum[blockIdx.x] = sc[255];
}

__global__ __launch_bounds__(256) void k_scan2(const int* __restrict__ blocksum,
                                               int* __restrict__ blockoff) {
    __shared__ int sc[256];
    int t = threadIdx.x;
    int v = (t < NB1) ? blocksum[t] : 0;
    sc[t] = v;
    __syncthreads();
    for (int off = 1; off < 256; off <<= 1) {
        int u = (t >= off) ? sc[t - off] : 0;
        __syncthreads();
        sc[t] += u;
        __syncthreads();
    }
    if (t < NB1) blockoff[t] = sc[t] - v;
}

// rowptr[i] += blockoff[i>>8]; cursor[i] = rowptr[i]; rowptr[N]=E
__global__ __launch_bounds__(256) void k_scan3(int* __restrict__ rowptr,
                                               const int* __restrict__ blockoff,
                                               int* __restrict__ cursor) {
    int i = blockIdx.x * 256 + threadIdx.x;
    if (i < N_NODES) {
        int r = rowptr[i] + blockoff[i >> 8];
        rowptr[i] = r;
        cursor[i] = r;
    }
    if (i == 0) rowptr[N_NODES] = N_EDGES;
}

// ---------------- scatter edges into CSR (by dst), with gauss-table index ----------------
__global__ void k_scatter(const int* __restrict__ src, const int* __restrict__ dst,
                          const int* __restrict__ deg, int* __restrict__ cursor,
                          int2* __restrict__ csr_e) {
    int e = blockIdx.x * blockDim.x + threadIdx.x;
    if (e >= N_EDGES) return;
    int s = src[e], d = dst[e];
    int p = atomicAdd(&cursor[d], 1);
    int ds = deg[s], dd = deg[d];
    int idx = (ds < 64 && dd < 64) ? (ds * 64 + dd) : -1;
    csr_e[p] = make_int2(s, idx);
}

// ---------------- gaussian from degrees (shared by table + fallback) ----------------
__device__ __forceinline__ float4 gauss_direct(int degs, int degd,
                                               const float* __restrict__ mu,
                                               const float* __restrict__ isg,
                                               const float* __restrict__ ppw,
                                               const float* __restrict__ ppb) {
    float p0 = rsqrtf((float)degs + 1.0f);
    float p1 = rsqrtf((float)degd + 1.0f);
    float u0 = tanhf(fmaf(p1, ppw[1], fmaf(p0, ppw[0], ppb[0])));
    float u1 = tanhf(fmaf(p1, ppw[3], fmaf(p0, ppw[2], ppb[1])));
    float4 g;
    float t0, t1;
    t0 = (u0 - mu[0]) * isg[0]; t1 = (u1 - mu[1]) * isg[1];
    g.x = __expf(-0.5f * (t0 * t0 + t1 * t1));
    t0 = (u0 - mu[2]) * isg[2]; t1 = (u1 - mu[3]) * isg[3];
    g.y = __expf(-0.5f * (t0 * t0 + t1 * t1));
    t0 = (u0 - mu[4]) * isg[4]; t1 = (u1 - mu[5]) * isg[5];
    g.z = __expf(-0.5f * (t0 * t0 + t1 * t1));
    g.w = 0.f;
    return g;
}

// all 4 layers' 64x64 gauss tables
__global__ __launch_bounds__(256) void k_tables(const float* __restrict__ mu,
                                                const float* __restrict__ isg,
                                                const float* __restrict__ ppw,
                                                const float* __restrict__ ppb,
                                                float4* __restrict__ tbl) {
    int i = blockIdx.x * 256 + threadIdx.x;  // 4*4096
    int l = i >> 12;
    int idx = i & 4095;
    tbl[i] = gauss_direct(idx >> 6, idx & 63, mu + l * 6, isg + l * 6,
                          ppw + l * 4, ppb + l * 2);
}

// ---------------- pull aggregation: one wave per node, no atomics ----------------
template <bool L0>
__global__ __launch_bounds__(256) void k_pull(const int* __restrict__ rowptr,
                                              const int2* __restrict__ csr_e,
                                              const float4* __restrict__ tbl,
                                              const float* __restrict__ h,
                                              const int* __restrict__ h_idx,
                                              const float* __restrict__ emb,
                                              const int* __restrict__ deg,
                                              const float* __restrict__ mu,
                                              const float* __restrict__ isg,
                                              const float* __restrict__ ppw,
                                              const float* __restrict__ ppb,
                                              float* __restrict__ a3) {
    int n = blockIdx.x * 4 + (threadIdx.x >> 6);
    n = __builtin_amdgcn_readfirstlane(n);
    if (n >= N_NODES) return;
    int lane = threadIdx.x & 63;
    int beg = rowptr[n];
    int end = rowptr[n + 1];
    int dd = end - beg;
    float a0 = 0.f, a1 = 0.f, a2 = 0.f;

    auto getg = [&](int2 r) -> float4 {
        if (__builtin_expect(r.y >= 0, 1)) return tbl[r.y];
        return gauss_direct(deg[r.x], dd, mu, isg, ppw, ppb);
    };
    auto geth = [&](int s) -> float {
        if (L0) return emb[h_idx[s] * HID + lane];
        return h[(size_t)s * HID + lane];
    };

    int p = beg;
    for (; p + 4 <= end; p += 4) {
        int2 r0 = csr_e[p], r1 = csr_e[p + 1], r2 = csr_e[p + 2], r3 = csr_e[p + 3];
        float h0 = geth(r0.x), h1 = geth(r1.x), h2 = geth(r2.x), h3 = geth(r3.x);
        float4 g0 = getg(r0), g1 = getg(r1), g2 = getg(r2), g3 = getg(r3);
        a0 = fmaf(g0.x, h0, a0); a1 = fmaf(g0.y, h0, a1); a2 = fmaf(g0.z, h0, a2);
        a0 = fmaf(g1.x, h1, a0); a1 = fmaf(g1.y, h1, a1); a2 = fmaf(g1.z, h1, a2);
        a0 = fmaf(g2.x, h2, a0); a1 = fmaf(g2.y, h2, a1); a2 = fmaf(g2.z, h2, a2);
        a0 = fmaf(g3.x, h3, a0); a1 = fmaf(g3.y, h3, a1); a2 = fmaf(g3.z, h3, a2);
    }
    for (; p < end; ++p) {
        int2 r0 = csr_e[p];
        float h0 = geth(r0.x);
        float4 g0 = getg(r0);
        a0 = fmaf(g0.x, h0, a0); a1 = fmaf(g0.y, h0, a1); a2 = fmaf(g0.z, h0, a2);
    }
    float* out = a3 + (size_t)n * KOUT + lane;
    out[0] = a0;
    out[64] = a1;
    out[128] = a2;
}

// ---------------- transform: agg = a3 @ W^T  (+ fused BN partial sums) ----------------
__global__ __launch_bounds__(256) void k_fc2(const float* __restrict__ a3,
                                             const float* __restrict__ fcw,
                                             float* __restrict__ agg,
                                             float* __restrict__ bnsum) {
    int t = threadIdx.x;
    int cp = t & 63;
    int q = t >> 6;
    float w[48];
#pragma unroll
    for (int jj = 0; jj < 48; ++jj) {
        int j = q * 48 + jj;
        w[jj] = fcw[((j >> 6) * 64 + cp) * 64 + (j & 63)];
    }
    __shared__ float4 sa4[48];
    __shared__ float sp[4][64];
    float bnS = 0.f, bnQ = 0.f;
    const float4* a3v = (const float4*)a3;
    for (int node = blockIdx.x; node < N_NODES; node += gridDim.x) {
        if (t < 48) sa4[t] = a3v[(size_t)node * 48 + t];
        __syncthreads();
        float acc = 0.f;
#pragma unroll
        for (int m = 0; m < 12; ++m) {
            float4 s4 = sa4[q * 12 + m];
            acc = fmaf(s4.x, w[4 * m + 0], acc);
            acc = fmaf(s4.y, w[4 * m + 1], acc);
            acc = fmaf(s4.z, w[4 * m + 2], acc);
            acc = fmaf(s4.w, w[4 * m + 3], acc);
        }
        sp[q][cp] = acc;
        __syncthreads();
        if (q == 0) {
            float v = sp[0][cp] + sp[1][cp] + sp[2][cp] + sp[3][cp];
            agg[(size_t)node * HID + cp] = v;
            bnS += v;
            bnQ += v * v;
        }
    }
    if (q == 0) {
        atomicAdd(&bnsum[cp], bnS);
        atomicAdd(&bnsum[64 + cp], bnQ);
    }
}

// ---------------- BN finalize + apply + residual (bnfin fused per-block) ----------------
template <bool L0>
__global__ __launch_bounds__(256) void k_bnapply(const float* __restrict__ agg,
                                                 const float* __restrict__ bnsum,
                                                 const float* __restrict__ bng,
                                                 const float* __restrict__ bnb,
                                                 const int* __restrict__ h_idx,
                                                 const float* __restrict__ emb,
                                                 float* __restrict__ h) {
    __shared__ float ssc[128];
    int t = threadIdx.x;
    if (t < 64) {
        const float invN = 1.0f / (float)N_NODES;
        float mean = bnsum[t] * invN;
        float var = bnsum[64 + t] * invN - mean * mean;
        float scale = bng[t] * rsqrtf(var + EPS);
        ssc[t] = scale;
        ssc[64 + t] = bnb[t] - mean * scale;
    }
    __syncthreads();
    int i = blockIdx.x * 256 + t;
    if (i < N_NODES * HID) {
        int c = i & 63;
        float hn = fmaf(agg[i], ssc[c], ssc[64 + c]);
        hn = fmaxf(hn, 0.f);
        if (L0) {
            int n = i >> 6;
            h[i] = emb[h_idx[n] * HID + c] + hn;
        } else {
            h[i] += hn;
        }
    }
}

// ---------------- readout: wave per 64-node chunk, run-length accumulate ----------------
__global__ __launch_bounds__(256) void k_readout(const float* __restrict__ h,
                                                 const int* __restrict__ gid,
                                                 float* __restrict__ hg,
                                                 float* __restrict__ cnt) {
    int chunk = blockIdx.x * 4 + (threadIdx.x >> 6);
    int lane = threadIdx.x & 63;
    int n0 = chunk * 64;
    if (n0 >= N_NODES) return;
    int n1 = min(n0 + 64, N_NODES);
    int curg = gid[n0];
    float acc = 0.f;
    int count = 0;
    for (int n = n0; n < n1; ++n) {
        int g = gid[n];
        if (g != curg) {
            atomicAdd(&hg[(size_t)curg * HID + lane], acc);
            if (lane == 0) atomicAdd(&cnt[curg], (float)count);
            curg = g; acc = 0.f; count = 0;
        }
        acc += h[(size_t)n * HID + lane];
        ++count;
    }
    atomicAdd(&hg[(size_t)curg * HID + lane], acc);
    if (lane == 0) atomicAdd(&cnt[curg], (float)count);
}

// ---------------- MLP readout ----------------
__global__ __launch_bounds__(256) void k_mlp(const float* __restrict__ hg,
                                             const float* __restrict__ cnt,
                                             const float* __restrict__ w1, const float* __restrict__ b1,
                                             const float* __restrict__ w2, const float* __restrict__ b2,
                                             const float* __restrict__ w3, const float* __restrict__ b3,
                                             float* __restrict__ out) {
    int g = threadIdx.x;  // 256 threads, single block
    float inv = 1.0f / fmaxf(cnt[g], 1.0f);
    float x[HID];
#pragma unroll
    for (int i = 0; i < HID; ++i) x[i] = hg[(size_t)g * HID + i] * inv;
    float y1[32];
#pragma unroll
    for (int j = 0; j < 32; ++j) {
        float acc = b1[j];
#pragma unroll
        for (int i = 0; i < HID; ++i) acc = fmaf(x[i], w1[j * HID + i], acc);
        y1[j] = fmaxf(acc, 0.f);
    }
    float y2[16];
#pragma unroll
    for (int j = 0; j < 16; ++j) {
        float acc = b2[j];
#pragma unroll
        for (int i = 0; i < 32; ++i) acc = fmaf(y1[i], w2[j * 32 + i], acc);
        y2[j] = fmaxf(acc, 0.f);
    }
    float acc = b3[0];
#pragma unroll
    for (int i = 0; i < 16; ++i) acc = fmaf(y2[i], w3[i], acc);
    out[g] = acc;
}

extern "C" void kernel_launch(void* const* d_in, const int* in_sizes, int n_in,
                              void* d_out, int out_size, void* d_ws, size_t ws_size,
                              hipStream_t stream) {
    const int* h_idx = (const int*)d_in[0];
    const int* src = (const int*)d_in[1];
    const int* dst = (const int*)d_in[2];
    const int* gid = (const int*)d_in[3];
    const float* emb = (const float*)d_in[4];
    const float* fc_w = (const float*)d_in[5];
    const float* mu = (const float*)d_in[6];
    const float* isg = (const float*)d_in[7];
    const float* bng = (const float*)d_in[8];
    const float* bnb = (const float*)d_in[9];
    const float* ppw = (const float*)d_in[10];
    const float* ppb = (const float*)d_in[11];
    const float* w1 = (const float*)d_in[12];
    const float* b1 = (const float*)d_in[13];
    const float* w2 = (const float*)d_in[14];
    const float* b2 = (const float*)d_in[15];
    const float* w3 = (const float*)d_in[16];
    const float* b3 = (const float*)d_in[17];

    char* ws = (char*)d_ws;
    size_t o = 0;
    auto take = [&](size_t bytes) -> char* {
        char* p = ws + o;
        o += (bytes + 255) & ~(size_t)255;
        return p;
    };
    int* deg = (int*)take((size_t)N_NODES * 4);
    int* cursor = (int*)take((size_t)N_NODES * 4);
    int* rowptr = (int*)take((size_t)(N_NODES + 1) * 4);
    int* blocksum = (int*)take((size_t)NB1 * 4);
    int* blockoff = (int*)take((size_t)NB1 * 4);
    int2* csr_e = (int2*)take((size_t)N_EDGES * 8);
    float4* tbl = (float4*)take((size_t)4 * 4096 * 16);
    float* h = (float*)take((size_t)N_NODES * HID * 4);
    float* a3 = (float*)take((size_t)N_NODES * KOUT * 4);
    float* agg = (float*)take((size_t)N_NODES * HID * 4);
    // bnsum(4*128) + hg + cnt contiguous -> one memset
    float* bnsum = (float*)take(4 * 128 * 4);
    float* hg = (float*)take((size_t)N_GRAPHS * HID * 4);
    float* cnt = (float*)take((size_t)N_GRAPHS * 4);

    hipMemsetAsync(deg, 0, (size_t)N_NODES * 4, stream);
    hipMemsetAsync(bnsum, 0, (4 * 128 + N_GRAPHS * HID + N_GRAPHS) * 4, stream);

    k_deg<<<(N_EDGES + 255) / 256, 256, 0, stream>>>(dst, deg);
    k_scan1<<<NB1, 256, 0, stream>>>(deg, rowptr, blocksum);
    k_scan2<<<1, 256, 0, stream>>>(blocksum, blockoff);
    k_scan3<<<NB1, 256, 0, stream>>>(rowptr, blockoff, cursor);
    k_scatter<<<(N_EDGES + 255) / 256, 256, 0, stream>>>(src, dst, deg, cursor, csr_e);
    k_tables<<<(4 * 4096) / 256, 256, 0, stream>>>(mu, isg, ppw, ppb, tbl);

    for (int l = 0; l < 4; ++l) {
        const float* mul = mu + l * 6;
        const float* isgl = isg + l * 6;
        const float* ppwl = ppw + l * 4;
        const float* ppbl = ppb + l * 2;
        const float4* tbll = tbl + (size_t)l * 4096;
        if (l == 0)
            k_pull<true><<<(N_NODES + 3) / 4, 256, 0, stream>>>(rowptr, csr_e, tbll, h,
                h_idx, emb, deg, mul, isgl, ppwl, ppbl, a3);
        else
            k_pull<false><<<(N_NODES + 3) / 4, 256, 0, stream>>>(rowptr, csr_e, tbll, h,
                h_idx, emb, deg, mul, isgl, ppwl, ppbl, a3);
        k_fc2<<<512, 256, 0, stream>>>(a3, fc_w + (size_t)l * KOUT * HID, agg,
                                       bnsum + l * 128);
        if (l == 0)
            k_bnapply<true><<<(N_NODES * HID + 255) / 256, 256, 0, stream>>>(
                agg, bnsum + l * 128, bng + l * 64, bnb + l * 64, h_idx, emb, h);
        else
            k_bnapply<false><<<(N_NODES * HID + 255) / 256, 256, 0, stream>>>(
                agg, bnsum + l * 128, bng + l * 64, bnb + l * 64, h_idx, emb, h);
    }

    k_readout<<<(N_NODES / 64 + 3) / 4 + 1, 256, 0, stream>>>(h, gid, hg, cnt);
    k_mlp<<<1, 256, 0, stream>>>(hg, cnt, w1, b1, w2, b2, w3, b3, (float*)d_out);
}

// Round 4
// 551.191 us; speedup vs baseline: 2.4445x; 1.2146x over previous
//
#include <hip/hip_runtime.h>
#include <hip/hip_bf16.h>

#define N_NODES 50000
#define N_EDGES 800000
#define N_GRAPHS 256
#define HID 64
#define KOUT 192   // K * OUT
#define EPS 1e-5f
#define NB1 196    // ceil(N_NODES / 256)

// ---------------- degree ----------------
__global__ void k_deg(const int* __restrict__ dst, int* __restrict__ deg) {
    int i = blockIdx.x * blockDim.x + threadIdx.x;
    if (i < N_EDGES) atomicAdd(&deg[dst[i]], 1);
}

// ---------------- hierarchical exclusive scan of deg -> rowptr ----------------
__global__ __launch_bounds__(256) void k_scan1(const int* __restrict__ deg,
                                               int* __restrict__ rowptr,
                                               int* __restrict__ blocksum) {
    __shared__ int sc[256];
    int t = threadIdx.x;
    int i = blockIdx.x * 256 + t;
    int v = (i < N_NODES) ? deg[i] : 0;
    sc[t] = v;
    __syncthreads();
    for (int off = 1; off < 256; off <<= 1) {
        int u = (t >= off) ? sc[t - off] : 0;
        __syncthreads();
        sc[t] += u;
        __syncthreads();
    }
    if (i < N_NODES) rowptr[i] = sc[t] - v;  // exclusive local prefix
    if (t == 255) blocksum[blockIdx.x] = sc[255];
}

__global__ __launch_bounds__(256) void k_scan2(const int* __restrict__ blocksum,
                                               int* __restrict__ blockoff) {
    __shared__ int sc[256];
    int t = threadIdx.x;
    int v = (t < NB1) ? blocksum[t] : 0;
    sc[t] = v;
    __syncthreads();
    for (int off = 1; off < 256; off <<= 1) {
        int u = (t >= off) ? sc[t - off] : 0;
        __syncthreads();
        sc[t] += u;
        __syncthreads();
    }
    if (t < NB1) blockoff[t] = sc[t] - v;
}

// rowptr[i] += blockoff[i>>8]; cursor[i] = rowptr[i]; rowptr[N]=E
__global__ __launch_bounds__(256) void k_scan3(int* __restrict__ rowptr,
                                               const int* __restrict__ blockoff,
                                               int* __restrict__ cursor) {
    int i = blockIdx.x * 256 + threadIdx.x;
    if (i < N_NODES) {
        int r = rowptr[i] + blockoff[i >> 8];
        rowptr[i] = r;
        cursor[i] = r;
    }
    if (i == 0) rowptr[N_NODES] = N_EDGES;
}

// ---------------- scatter edges into CSR (by dst), with gauss-table index ----------------
__global__ void k_scatter(const int* __restrict__ src, const int* __restrict__ dst,
                          const int* __restrict__ deg, int* __restrict__ cursor,
                          int2* __restrict__ csr_e) {
    int e = blockIdx.x * blockDim.x + threadIdx.x;
    if (e >= N_EDGES) return;
    int s = src[e], d = dst[e];
    int p = atomicAdd(&cursor[d], 1);
    int ds = deg[s], dd = deg[d];
    int idx = (ds < 64 && dd < 64) ? (ds * 64 + dd) : -1;
    csr_e[p] = make_int2(s, idx);
}

// ---------------- gaussian from degrees (shared by table + fallback) ----------------
__device__ __forceinline__ float4 gauss_direct(int degs, int degd,
                                               const float* __restrict__ mu,
                                               const float* __restrict__ isg,
                                               const float* __restrict__ ppw,
                                               const float* __restrict__ ppb) {
    float p0 = rsqrtf((float)degs + 1.0f);
    float p1 = rsqrtf((float)degd + 1.0f);
    float u0 = tanhf(fmaf(p1, ppw[1], fmaf(p0, ppw[0], ppb[0])));
    float u1 = tanhf(fmaf(p1, ppw[3], fmaf(p0, ppw[2], ppb[1])));
    float4 g;
    float t0, t1;
    t0 = (u0 - mu[0]) * isg[0]; t1 = (u1 - mu[1]) * isg[1];
    g.x = __expf(-0.5f * (t0 * t0 + t1 * t1));
    t0 = (u0 - mu[2]) * isg[2]; t1 = (u1 - mu[3]) * isg[3];
    g.y = __expf(-0.5f * (t0 * t0 + t1 * t1));
    t0 = (u0 - mu[4]) * isg[4]; t1 = (u1 - mu[5]) * isg[5];
    g.z = __expf(-0.5f * (t0 * t0 + t1 * t1));
    g.w = 0.f;
    return g;
}

// all 4 layers' 64x64 gauss tables
__global__ __launch_bounds__(256) void k_tables(const float* __restrict__ mu,
                                                const float* __restrict__ isg,
                                                const float* __restrict__ ppw,
                                                const float* __restrict__ ppb,
                                                float4* __restrict__ tbl) {
    int i = blockIdx.x * 256 + threadIdx.x;  // 4*4096
    int l = i >> 12;
    int idx = i & 4095;
    tbl[i] = gauss_direct(idx >> 6, idx & 63, mu + l * 6, isg + l * 6,
                          ppw + l * 4, ppb + l * 2);
}

// ---------------- pull aggregation: one wave per node, no atomics ----------------
template <bool L0>
__global__ __launch_bounds__(256) void k_pull(const int* __restrict__ rowptr,
                                              const int2* __restrict__ csr_e,
                                              const float4* __restrict__ tbl,
                                              const float* __restrict__ h,
                                              const int* __restrict__ h_idx,
                                              const float* __restrict__ emb,
                                              const int* __restrict__ deg,
                                              const float* __restrict__ mu,
                                              const float* __restrict__ isg,
                                              const float* __restrict__ ppw,
                                              const float* __restrict__ ppb,
                                              float* __restrict__ a3) {
    int n = blockIdx.x * 4 + (threadIdx.x >> 6);
    n = __builtin_amdgcn_readfirstlane(n);
    if (n >= N_NODES) return;
    int lane = threadIdx.x & 63;
    int beg = rowptr[n];
    int end = rowptr[n + 1];
    int dd = end - beg;
    float a0 = 0.f, a1 = 0.f, a2 = 0.f;

    auto getg = [&](int2 r) -> float4 {
        if (__builtin_expect(r.y >= 0, 1)) return tbl[r.y];
        return gauss_direct(deg[r.x], dd, mu, isg, ppw, ppb);
    };
    auto geth = [&](int s) -> float {
        if (L0) return emb[h_idx[s] * HID + lane];
        return h[(size_t)s * HID + lane];
    };

    int p = beg;
    for (; p + 4 <= end; p += 4) {
        int2 r0 = csr_e[p], r1 = csr_e[p + 1], r2 = csr_e[p + 2], r3 = csr_e[p + 3];
        float h0 = geth(r0.x), h1 = geth(r1.x), h2 = geth(r2.x), h3 = geth(r3.x);
        float4 g0 = getg(r0), g1 = getg(r1), g2 = getg(r2), g3 = getg(r3);
        a0 = fmaf(g0.x, h0, a0); a1 = fmaf(g0.y, h0, a1); a2 = fmaf(g0.z, h0, a2);
        a0 = fmaf(g1.x, h1, a0); a1 = fmaf(g1.y, h1, a1); a2 = fmaf(g1.z, h1, a2);
        a0 = fmaf(g2.x, h2, a0); a1 = fmaf(g2.y, h2, a1); a2 = fmaf(g2.z, h2, a2);
        a0 = fmaf(g3.x, h3, a0); a1 = fmaf(g3.y, h3, a1); a2 = fmaf(g3.z, h3, a2);
    }
    for (; p < end; ++p) {
        int2 r0 = csr_e[p];
        float h0 = geth(r0.x);
        float4 g0 = getg(r0);
        a0 = fmaf(g0.x, h0, a0); a1 = fmaf(g0.y, h0, a1); a2 = fmaf(g0.z, h0, a2);
    }
    float* out = a3 + (size_t)n * KOUT + lane;
    out[0] = a0;
    out[64] = a1;
    out[128] = a2;
}

// ---------------- transform: agg = a3 @ W^T  (+ fused BN partial sums) ----------------
// Block: 256 threads = 4 waves; wave q owns j-range [q*48, q*48+48) with weights in regs.
// 16 nodes per barrier pair; all threads stage, all threads finalize (4 nodes each).
#define FC2_TILE 64
#define FC2_BATCH 16
__global__ __launch_bounds__(256) void k_fc2(const float* __restrict__ a3,
                                             const float* __restrict__ fcw,
                                             float* __restrict__ agg,
                                             float* __restrict__ bnsum) {
    int t = threadIdx.x;
    int cp = t & 63;
    int q = t >> 6;
    float w[48];
#pragma unroll
    for (int jj = 0; jj < 48; ++jj) {
        int j = q * 48 + jj;
        w[jj] = fcw[((j >> 6) * 64 + cp) * 64 + (j & 63)];
    }
    __shared__ float4 sa4[FC2_BATCH][48];   // 12 KB
    __shared__ float sp[4][FC2_BATCH][64];  // 16 KB
    float bnS = 0.f, bnQ = 0.f;
    const float4* a3v = (const float4*)a3;
    int n0 = blockIdx.x * FC2_TILE;
    for (int nb = 0; nb < FC2_TILE; nb += FC2_BATCH) {
        int base = n0 + nb;
        // stage 16 nodes x 48 float4 (768 total -> 3 per thread, coalesced)
#pragma unroll
        for (int ii = 0; ii < 3; ++ii) {
            int i = t + ii * 256;
            int nn = i / 48, jj = i - nn * 48;
            int node = base + nn;
            sa4[nn][jj] = (node < N_NODES) ? a3v[(size_t)node * 48 + jj]
                                           : make_float4(0.f, 0.f, 0.f, 0.f);
        }
        __syncthreads();
        float acc[FC2_BATCH];
#pragma unroll
        for (int nn = 0; nn < FC2_BATCH; ++nn) acc[nn] = 0.f;
#pragma unroll
        for (int m = 0; m < 12; ++m) {
            float w0 = w[4 * m], w1 = w[4 * m + 1], w2 = w[4 * m + 2], w3 = w[4 * m + 3];
#pragma unroll
            for (int nn = 0; nn < FC2_BATCH; ++nn) {
                float4 s4 = sa4[nn][q * 12 + m];  // wave-wide broadcast, conflict-free
                acc[nn] = fmaf(s4.x, w0, acc[nn]);
                acc[nn] = fmaf(s4.y, w1, acc[nn]);
                acc[nn] = fmaf(s4.z, w2, acc[nn]);
                acc[nn] = fmaf(s4.w, w3, acc[nn]);
            }
        }
#pragma unroll
        for (int nn = 0; nn < FC2_BATCH; ++nn) sp[q][nn][cp] = acc[nn];
        __syncthreads();
        // finalize: each thread handles 4 nodes (quarter q -> nodes q*4..q*4+3)
#pragma unroll
        for (int i = 0; i < 4; ++i) {
            int nn = q * 4 + i;
            int node = base + nn;
            if (node < N_NODES) {
                float v = sp[0][nn][cp] + sp[1][nn][cp] + sp[2][nn][cp] + sp[3][nn][cp];
                agg[(size_t)node * HID + cp] = v;
                bnS += v;
                bnQ += v * v;
            }
        }
        __syncthreads();  // protect sa4/sp for next iteration
    }
    // block-local reduce of BN partials across the 4 waves, then one atomic per channel
    sp[q][0][cp] = bnS;
    sp[q][1][cp] = bnQ;
    __syncthreads();
    if (q == 0) {
        float S = sp[0][0][cp] + sp[1][0][cp] + sp[2][0][cp] + sp[3][0][cp];
        float Q = sp[0][1][cp] + sp[1][1][cp] + sp[2][1][cp] + sp[3][1][cp];
        atomicAdd(&bnsum[cp], S);
        atomicAdd(&bnsum[64 + cp], Q);
    }
}

// ---------------- BN finalize + apply + residual (bnfin fused per-block) ----------------
template <bool L0>
__global__ __launch_bounds__(256) void k_bnapply(const float* __restrict__ agg,
                                                 const float* __restrict__ bnsum,
                                                 const float* __restrict__ bng,
                                                 const float* __restrict__ bnb,
                                                 const int* __restrict__ h_idx,
                                                 const float* __restrict__ emb,
                                                 float* __restrict__ h) {
    __shared__ float ssc[128];
    int t = threadIdx.x;
    if (t < 64) {
        const float invN = 1.0f / (float)N_NODES;
        float mean = bnsum[t] * invN;
        float var = bnsum[64 + t] * invN - mean * mean;
        float scale = bng[t] * rsqrtf(var + EPS);
        ssc[t] = scale;
        ssc[64 + t] = bnb[t] - mean * scale;
    }
    __syncthreads();
    int i = blockIdx.x * 256 + t;
    if (i < N_NODES * HID) {
        int c = i & 63;
        float hn = fmaf(agg[i], ssc[c], ssc[64 + c]);
        hn = fmaxf(hn, 0.f);
        if (L0) {
            int n = i >> 6;
            h[i] = emb[h_idx[n] * HID + c] + hn;
        } else {
            h[i] += hn;
        }
    }
}

// ---------------- readout: wave per 64-node chunk, run-length accumulate ----------------
__global__ __launch_bounds__(256) void k_readout(const float* __restrict__ h,
                                                 const int* __restrict__ gid,
                                                 float* __restrict__ hg,
                                                 float* __restrict__ cnt) {
    int chunk = blockIdx.x * 4 + (threadIdx.x >> 6);
    int lane = threadIdx.x & 63;
    int n0 = chunk * 64;
    if (n0 >= N_NODES) return;
    int n1 = min(n0 + 64, N_NODES);
    int curg = gid[n0];
    float acc = 0.f;
    int count = 0;
    for (int n = n0; n < n1; ++n) {
        int g = gid[n];
        if (g != curg) {
            atomicAdd(&hg[(size_t)curg * HID + lane], acc);
            if (lane == 0) atomicAdd(&cnt[curg], (float)count);
            curg = g; acc = 0.f; count = 0;
        }
        acc += h[(size_t)n * HID + lane];
        ++count;
    }
    atomicAdd(&hg[(size_t)curg * HID + lane], acc);
    if (lane == 0) atomicAdd(&cnt[curg], (float)count);
}

// ---------------- MLP readout ----------------
__global__ __launch_bounds__(256) void k_mlp(const float* __restrict__ hg,
                                             const float* __restrict__ cnt,
                                             const float* __restrict__ w1, const float* __restrict__ b1,
                                             const float* __restrict__ w2, const float* __restrict__ b2,
                                             const float* __restrict__ w3, const float* __restrict__ b3,
                                             float* __restrict__ out) {
    int g = threadIdx.x;  // 256 threads, single block
    float inv = 1.0f / fmaxf(cnt[g], 1.0f);
    float x[HID];
#pragma unroll
    for (int i = 0; i < HID; ++i) x[i] = hg[(size_t)g * HID + i] * inv;
    float y1[32];
#pragma unroll
    for (int j = 0; j < 32; ++j) {
        float acc = b1[j];
#pragma unroll
        for (int i = 0; i < HID; ++i) acc = fmaf(x[i], w1[j * HID + i], acc);
        y1[j] = fmaxf(acc, 0.f);
    }
    float y2[16];
#pragma unroll
    for (int j = 0; j < 16; ++j) {
        float acc = b2[j];
#pragma unroll
        for (int i = 0; i < 32; ++i) acc = fmaf(y1[i], w2[j * 32 + i], acc);
        y2[j] = fmaxf(acc, 0.f);
    }
    float acc = b3[0];
#pragma unroll
    for (int i = 0; i < 16; ++i) acc = fmaf(y2[i], w3[i], acc);
    out[g] = acc;
}

extern "C" void kernel_launch(void* const* d_in, const int* in_sizes, int n_in,
                              void* d_out, int out_size, void* d_ws, size_t ws_size,
                              hipStream_t stream) {
    const int* h_idx = (const int*)d_in[0];
    const int* src = (const int*)d_in[1];
    const int* dst = (const int*)d_in[2];
    const int* gid = (const int*)d_in[3];
    const float* emb = (const float*)d_in[4];
    const float* fc_w = (const float*)d_in[5];
    const float* mu = (const float*)d_in[6];
    const float* isg = (const float*)d_in[7];
    const float* bng = (const float*)d_in[8];
    const float* bnb = (const float*)d_in[9];
    const float* ppw = (const float*)d_in[10];
    const float* ppb = (const float*)d_in[11];
    const float* w1 = (const float*)d_in[12];
    const float* b1 = (const float*)d_in[13];
    const float* w2 = (const float*)d_in[14];
    const float* b2 = (const float*)d_in[15];
    const float* w3 = (const float*)d_in[16];
    const float* b3 = (const float*)d_in[17];

    char* ws = (char*)d_ws;
    size_t o = 0;
    auto take = [&](size_t bytes) -> char* {
        char* p = ws + o;
        o += (bytes + 255) & ~(size_t)255;
        return p;
    };
    int* deg = (int*)take((size_t)N_NODES * 4);
    int* cursor = (int*)take((size_t)N_NODES * 4);
    int* rowptr = (int*)take((size_t)(N_NODES + 1) * 4);
    int* blocksum = (int*)take((size_t)NB1 * 4);
    int* blockoff = (int*)take((size_t)NB1 * 4);
    int2* csr_e = (int2*)take((size_t)N_EDGES * 8);
    float4* tbl = (float4*)take((size_t)4 * 4096 * 16);
    float* h = (float*)take((size_t)N_NODES * HID * 4);
    float* a3 = (float*)take((size_t)N_NODES * KOUT * 4);
    float* agg = (float*)take((size_t)N_NODES * HID * 4);
    // bnsum(4*128) + hg + cnt contiguous -> one memset
    float* bnsum = (float*)take(4 * 128 * 4);
    float* hg = (float*)take((size_t)N_GRAPHS * HID * 4);
    float* cnt = (float*)take((size_t)N_GRAPHS * 4);

    hipMemsetAsync(deg, 0, (size_t)N_NODES * 4, stream);
    hipMemsetAsync(bnsum, 0, (4 * 128 + N_GRAPHS * HID + N_GRAPHS) * 4, stream);

    k_deg<<<(N_EDGES + 255) / 256, 256, 0, stream>>>(dst, deg);
    k_scan1<<<NB1, 256, 0, stream>>>(deg, rowptr, blocksum);
    k_scan2<<<1, 256, 0, stream>>>(blocksum, blockoff);
    k_scan3<<<NB1, 256, 0, stream>>>(rowptr, blockoff, cursor);
    k_scatter<<<(N_EDGES + 255) / 256, 256, 0, stream>>>(src, dst, deg, cursor, csr_e);
    k_tables<<<(4 * 4096) / 256, 256, 0, stream>>>(mu, isg, ppw, ppb, tbl);

    for (int l = 0; l < 4; ++l) {
        const float* mul = mu + l * 6;
        const float* isgl = isg + l * 6;
        const float* ppwl = ppw + l * 4;
        const float* ppbl = ppb + l * 2;
        const float4* tbll = tbl + (size_t)l * 4096;
        if (l == 0)
            k_pull<true><<<(N_NODES + 3) / 4, 256, 0, stream>>>(rowptr, csr_e, tbll, h,
                h_idx, emb, deg, mul, isgl, ppwl, ppbl, a3);
        else
            k_pull<false><<<(N_NODES + 3) / 4, 256, 0, stream>>>(rowptr, csr_e, tbll, h,
                h_idx, emb, deg, mul, isgl, ppwl, ppbl, a3);
        k_fc2<<<(N_NODES + FC2_TILE - 1) / FC2_TILE, 256, 0, stream>>>(
            a3, fc_w + (size_t)l * KOUT * HID, agg, bnsum + l * 128);
        if (l == 0)
            k_bnapply<true><<<(N_NODES * HID + 255) / 256, 256, 0, stream>>>(
                agg, bnsum + l * 128, bng + l * 64, bnb + l * 64, h_idx, emb, h);
        else
            k_bnapply<false><<<(N_NODES * HID + 255) / 256, 256, 0, stream>>>(
                agg, bnsum + l * 128, bng + l * 64, bnb + l * 64, h_idx, emb, h);
    }

    k_readout<<<(N_NODES / 64 + 3) / 4 + 1, 256, 0, stream>>>(h, gid, hg, cnt);
    k_mlp<<<1, 256, 0, stream>>>(hg, cnt, w1, b1, w2, b2, w3, b3, (float*)d_out);
}